// Round 1
// baseline (294.372 us; speedup 1.0000x reference)
//
#include <hip/hip_runtime.h>

// Problem constants (from reference): B=4, C=3, H=512, W=960, K2=16 -> K=4
#define BB 4
#define CC 3
#define HH 512
#define WW 960
#define HW (HH * WW)
#define NPIX (BB * HW)

__global__ __launch_bounds__(256)
void filter_interp_kernel(const float* __restrict__ inp,
                          const float* __restrict__ flow,
                          const float* __restrict__ filt,
                          float* __restrict__ out) {
    int tid = blockIdx.x * blockDim.x + threadIdx.x;
    if (tid >= NPIX) return;

    int b   = tid / HW;
    int rem = tid - b * HW;
    int y   = rem / WW;
    int x   = rem - y * WW;

    const float fx = flow[(b * 2 + 0) * HW + rem];
    const float fy = flow[(b * 2 + 1) * HW + rem];
    const float x2 = (float)x + fx;
    const float y2 = (float)y + fy;

    bool valid = (x2 >= 0.0f) && (x2 <= (float)(WW - 1)) &&
                 (y2 >= 0.0f) && (y2 <= (float)(HH - 1)) &&
                 (fabsf(fx) < (float)WW * 0.5f) &&
                 (fabsf(fy) < (float)HH * 0.5f);

    const int outbase = b * CC * HW + rem;
    if (!valid) {
        out[outbase]          = 0.0f;
        out[outbase + HW]     = 0.0f;
        out[outbase + 2 * HW] = 0.0f;
        return;
    }

    const int ix = (int)floorf(x2);
    const int iy = (int)floorf(y2);
    const float alpha = x2 - (float)ix;
    const float beta  = y2 - (float)iy;

    const float wTL = (1.0f - alpha) * (1.0f - beta);
    const float wTR = alpha * (1.0f - beta);
    const float wBL = (1.0f - alpha) * beta;
    const float wBR = alpha * beta;

    // Clipped patch coordinates: rows R[0..4], cols S[0..4]
    const int ixL0 = ix - 1;  // ix + 1 - K/2, K=4
    const int iyT0 = iy - 1;
    int S[5], R[5];
#pragma unroll
    for (int i = 0; i < 5; ++i) {
        S[i] = min(max(ixL0 + i, 0), WW - 1);
        R[i] = min(max(iyT0 + i, 0), HH - 1);
    }

    // Fold 16 filter taps x 4 bilinear weights into a 5x5 weight map
    // (channel-independent).
    float Wm[5][5];
#pragma unroll
    for (int j = 0; j < 5; ++j)
#pragma unroll
        for (int i = 0; i < 5; ++i) Wm[j][i] = 0.0f;

    const float* fptr = filt + (size_t)b * 16 * HW + rem;
#pragma unroll
    for (int dj = 0; dj < 4; ++dj) {
#pragma unroll
        for (int di = 0; di < 4; ++di) {
            const float f = fptr[(size_t)(dj * 4 + di) * HW];
            Wm[dj][di]         += f * wTL;
            Wm[dj][di + 1]     += f * wTR;
            Wm[dj + 1][di]     += f * wBL;
            Wm[dj + 1][di + 1] += f * wBR;
        }
    }

    // Per channel: gather the 5x5 patch, dot with the weight map.
    const float* ibase = inp + (size_t)b * CC * HW;
#pragma unroll
    for (int c = 0; c < CC; ++c) {
        const float* ic = ibase + (size_t)c * HW;
        float acc = 0.0f;
#pragma unroll
        for (int j = 0; j < 5; ++j) {
            const float* row = ic + (size_t)R[j] * WW;
#pragma unroll
            for (int i = 0; i < 5; ++i) {
                acc += row[S[i]] * Wm[j][i];
            }
        }
        out[outbase + (size_t)c * HW] = acc;
    }
}

extern "C" void kernel_launch(void* const* d_in, const int* in_sizes, int n_in,
                              void* d_out, int out_size, void* d_ws, size_t ws_size,
                              hipStream_t stream) {
    const float* teninput  = (const float*)d_in[0];
    const float* tenflow   = (const float*)d_in[1];
    const float* tenfilter = (const float*)d_in[2];
    float* out = (float*)d_out;

    const int threads = 256;
    const int blocks  = (NPIX + threads - 1) / threads;
    filter_interp_kernel<<<blocks, threads, 0, stream>>>(teninput, tenflow, tenfilter, out);
}

// Round 2
// 236.908 us; speedup vs baseline: 1.2426x; 1.2426x over previous
//
#include <hip/hip_runtime.h>

// Problem constants: B=4, C=3, H=512, W=960, K2=16 -> K=4
#define BB 4
#define CC 3
#define HH 512
#define WW 960
#define HW (HH * WW)
#define NPIX (BB * HW)

__global__ __launch_bounds__(256)
void filter_interp_kernel(const float* __restrict__ inp,
                          const float* __restrict__ flow,
                          const float* __restrict__ filt,
                          float* __restrict__ out) {
    int tid = blockIdx.x * blockDim.x + threadIdx.x;
    if (tid >= NPIX) return;

    int b   = tid / HW;
    int rem = tid - b * HW;
    int y   = rem / WW;
    int x   = rem - y * WW;

    const float fx = flow[(b * 2 + 0) * HW + rem];
    const float fy = flow[(b * 2 + 1) * HW + rem];
    const float x2 = (float)x + fx;
    const float y2 = (float)y + fy;

    bool valid = (x2 >= 0.0f) && (x2 <= (float)(WW - 1)) &&
                 (y2 >= 0.0f) && (y2 <= (float)(HH - 1)) &&
                 (fabsf(fx) < (float)WW * 0.5f) &&
                 (fabsf(fy) < (float)HH * 0.5f);

    const int outbase = b * CC * HW + rem;
    if (!valid) {
        out[outbase]          = 0.0f;
        out[outbase + HW]     = 0.0f;
        out[outbase + 2 * HW] = 0.0f;
        return;
    }

    const int ix = (int)floorf(x2);
    const int iy = (int)floorf(y2);
    const float alpha = x2 - (float)ix;
    const float beta  = y2 - (float)iy;

    const float wTL = (1.0f - alpha) * (1.0f - beta);
    const float wTR = alpha * (1.0f - beta);
    const float wBL = (1.0f - alpha) * beta;
    const float wBR = alpha * beta;

    const int ixL0 = ix - 1;
    const int iyT0 = iy - 1;

    // Vertically clamped row indices (always needed; row duplication at the
    // vertical border matches the reference's per-tap clip).
    int R[5];
#pragma unroll
    for (int j = 0; j < 5; ++j) R[j] = min(max(iyT0 + j, 0), HH - 1);

    // Fold 16 filter taps x 4 bilinear weights into a 5x5 weight map
    // (channel-independent).
    float Wm[5][5];
#pragma unroll
    for (int j = 0; j < 5; ++j)
#pragma unroll
        for (int i = 0; i < 5; ++i) Wm[j][i] = 0.0f;

    const float* fptr = filt + (size_t)b * 16 * HW + rem;
#pragma unroll
    for (int dj = 0; dj < 4; ++dj) {
#pragma unroll
        for (int di = 0; di < 4; ++di) {
            const float f = fptr[(size_t)(dj * 4 + di) * HW];
            Wm[dj][di]         += f * wTL;
            Wm[dj][di + 1]     += f * wTR;
            Wm[dj + 1][di]     += f * wBL;
            Wm[dj + 1][di + 1] += f * wBR;
        }
    }

    const float* ibase = inp + (size_t)b * CC * HW;
    float acc[3] = {0.0f, 0.0f, 0.0f};

    // Fast path: no horizontal clamping. Columns ixL0..ixL0+4 are contiguous
    // and sit inside the aligned 8-float window [a0, a0+8).
    if (ixL0 >= 0 && ixL0 + 4 <= WW - 1) {
        const int a0 = ixL0 & ~3;      // 16B-aligned, a0 >= 0, a0+7 <= WW-1
        const int o  = ixL0 - a0;      // 0..3

        // Barrel-shift each 5-wide weight row into an 8-wide extended row:
        // We[j][i] = Wm[j][i-o] for i-o in [0,4], else 0.
        const bool s2 = (o & 2) != 0;
        const bool s1 = (o & 1) != 0;
        float We[5][8];
#pragma unroll
        for (int j = 0; j < 5; ++j) {
            float t[8];
#pragma unroll
            for (int i = 0; i < 8; ++i) t[i] = (i < 5) ? Wm[j][i] : 0.0f;
            float u[8];
#pragma unroll
            for (int i = 0; i < 8; ++i)
                u[i] = s2 ? ((i >= 2) ? t[i - 2] : 0.0f) : t[i];
#pragma unroll
            for (int i = 0; i < 8; ++i)
                We[j][i] = s1 ? ((i >= 1) ? u[i - 1] : 0.0f) : u[i];
        }

#pragma unroll
        for (int j = 0; j < 5; ++j) {
            const size_t rowoff = (size_t)R[j] * WW + a0;
#pragma unroll
            for (int c = 0; c < CC; ++c) {
                const float* rp = ibase + (size_t)c * HW + rowoff;
                const float4 p0 = *(const float4*)(rp);
                const float4 p1 = *(const float4*)(rp + 4);
                float a = acc[c];
                a += p0.x * We[j][0];
                a += p0.y * We[j][1];
                a += p0.z * We[j][2];
                a += p0.w * We[j][3];
                a += p1.x * We[j][4];
                a += p1.y * We[j][5];
                a += p1.z * We[j][6];
                a += p1.w * We[j][7];
                acc[c] = a;
            }
        }
    } else {
        // Slow path (warped patch crosses the horizontal border): scalar
        // clamped gathers, identical to the verified round-1 logic.
        int S[5];
#pragma unroll
        for (int i = 0; i < 5; ++i) S[i] = min(max(ixL0 + i, 0), WW - 1);
#pragma unroll
        for (int c = 0; c < CC; ++c) {
            const float* ic = ibase + (size_t)c * HW;
            float a = 0.0f;
#pragma unroll
            for (int j = 0; j < 5; ++j) {
                const float* row = ic + (size_t)R[j] * WW;
#pragma unroll
                for (int i = 0; i < 5; ++i) a += row[S[i]] * Wm[j][i];
            }
            acc[c] = a;
        }
    }

    out[outbase]          = acc[0];
    out[outbase + HW]     = acc[1];
    out[outbase + 2 * HW] = acc[2];
}

extern "C" void kernel_launch(void* const* d_in, const int* in_sizes, int n_in,
                              void* d_out, int out_size, void* d_ws, size_t ws_size,
                              hipStream_t stream) {
    const float* teninput  = (const float*)d_in[0];
    const float* tenflow   = (const float*)d_in[1];
    const float* tenfilter = (const float*)d_in[2];
    float* out = (float*)d_out;

    const int threads = 256;
    const int blocks  = (NPIX + threads - 1) / threads;
    filter_interp_kernel<<<blocks, threads, 0, stream>>>(teninput, tenflow, tenfilter, out);
}